// Round 8
// baseline (143.112 us; speedup 1.0000x reference)
//
#include <hip/hip_runtime.h>
#include <hip/hip_bf16.h>
#include <math.h>

#define VOCAB 100000
#define TOPK  20
#define EMB   300
#define NTOK  (64*256)
#define NB    1563          // ceil(VOCAB/64) v-tiles
#define NSLICE 128          // v-tile slices (blocks per e-half)

typedef __attribute__((ext_vector_type(8))) short short8;   // 8 bf16 = 4 VGPR
typedef __attribute__((ext_vector_type(4))) short short4v;  // 8 B
typedef __attribute__((ext_vector_type(4))) float f32x4;

static __device__ inline short f2bf(float f) {
    __hip_bfloat16 h = __float2bfloat16(f);
    short s; __builtin_memcpy(&s, &h, 2);
    return s;
}

// ---------------------------------------------------------------------------
// prep: aT[e][d] = bf16(a[d][e]), zero-padded to 320x320.
// ---------------------------------------------------------------------------
__global__ void prep_kernel(const float* __restrict__ A, short* __restrict__ aT)
{
    const int e = blockIdx.x;                 // 0..319
    for (int d = threadIdx.x; d < 320; d += 256) {
        float f = (e < EMB && d < EMB) ? A[(size_t)d * EMB + e] : 0.f;
        aT[e * 320 + d] = f2bf(f);
    }
}

// ---------------------------------------------------------------------------
// score: s[v] = sum_e tanh( emb[v,:] . a[:,e] ) * b[e]  via bf16 MFMA.
// Persistent: 256 blocks (1/CU), block = (eh, slice). B-FRAGMENTS LIVE IN
// REGISTERS (bAll[5][5] short8 = 100 VGPR/lane, loaded once from L2-resident
// aT) -> k-loop reads ONLY A-frags from LDS (10 b128/wave/tile vs 35 in r7).
// Waves: 2mg x 2ng x 2kh; wave tile 32 rows x 80 cols, k-half 160.
// kh-exchange combine: wave kh ships acc[mt=1-kh] via float4 scratch (its own
// 40 KB region -> next-tile A staging overlaps the combine window), keeps
// mt=kh; tanh/shfl epilogue split across both kh groups.
// ---------------------------------------------------------------------------
__global__ __launch_bounds__(512, 2) void score_kernel(
    const float* __restrict__ emb, const short* __restrict__ aT,
    const float* __restrict__ B, float* __restrict__ S0, float* __restrict__ S1)
{
    __shared__ short8 EsS[64 * 40];          // 40960 B : A tile (swizzled)
    __shared__ float4 Scr[2 * 5 * 4 * 64];   // 40960 B : kh-exchange scratch
    __shared__ float  Sred[128];

    const int t     = threadIdx.x;
    const int eh    = blockIdx.x >> 7;   // 0..1 e-half
    const int slice = blockIdx.x & 127;  // 0..127

    const int lid = t & 63;
    const int w   = t >> 6;        // 0..7
    const int kh  = w >> 2;        // k-half 0..1
    const int mg  = (w >> 1) & 1;  // m-pair
    const int ng  = w & 1;         // n-group
    const int lm  = lid & 15;
    const int lk  = lid >> 4;
    const int kb    = kh * 20;     // k-chunk base
    const int xmask = lm & 7;      // rowA%8 == lm%8
    const int cell  = mg * 2 + ng;

    // ---- B-fragments -> registers, once per block (25 x b128 from L2)
    const short8* aT8 = (const short8*)aT;
    short8 bAll[5][5];
#pragma unroll
    for (int g = 0; g < 5; ++g) {
        const int e = eh * 160 + ng * 80 + g * 16 + lm;
#pragma unroll
        for (int ks = 0; ks < 5; ++ks)
            bAll[g][ks] = aT8[e * 40 + kb + ks * 4 + lk];
    }

    float bcol[5];
#pragma unroll
    for (int g = 0; g < 5; ++g) {
        const int e = eh * 160 + ng * 80 + g * 16 + lm;
        bcol[g] = (e < EMB) ? B[e] : 0.f;
    }
    int rb[2];
#pragma unroll
    for (int mt = 0; mt < 2; ++mt)
        rb[mt] = (mg * 32 + mt * 16 + lm) * 40;

    const int ntiles = (NB - slice + NSLICE - 1) / NSLICE;

    // ---- A prefetch (registers): 2368 full pair-chunks + 64 tail float4
    float4 pf[5][2]; float4 pft;
    const int i0 = t, i1 = t + 512, i2 = t + 1024, i3 = t + 1536, i4 = t + 2048;

#define ISSUE_PF(tn) do {                                                     \
    const float4* esrc = (const float4*)(emb + (size_t)(tn) * 64 * EMB);      \
    _Pragma("unroll")                                                         \
    for (int j = 0; j < 5; ++j) {                                             \
        const int i = t + j * 512;                                            \
        const int row = i / 37, cc = i - row * 37;                            \
        const bool ok = (i < 2368) && ((tn) * 64 + row < VOCAB);              \
        pf[j][0] = ok ? esrc[row * 75 + cc * 2]     : make_float4(0,0,0,0);   \
        pf[j][1] = ok ? esrc[row * 75 + cc * 2 + 1] : make_float4(0,0,0,0);   \
    }                                                                         \
    if (t < 64) pft = ((tn) * 64 + t < VOCAB) ? esrc[t * 75 + 74]             \
                                              : make_float4(0,0,0,0);         \
} while (0)

#define STAGE() do {                                                          \
    _Pragma("unroll")                                                         \
    for (int j = 0; j < 5; ++j) {                                             \
        const int i = t + j * 512;                                            \
        if (i < 2368) {                                                       \
            const int row = i / 37, cc = i - row * 37;                        \
            short8 val;                                                       \
            val[0]=f2bf(pf[j][0].x); val[1]=f2bf(pf[j][0].y);                 \
            val[2]=f2bf(pf[j][0].z); val[3]=f2bf(pf[j][0].w);                 \
            val[4]=f2bf(pf[j][1].x); val[5]=f2bf(pf[j][1].y);                 \
            val[6]=f2bf(pf[j][1].z); val[7]=f2bf(pf[j][1].w);                 \
            EsS[row * 40 + (cc ^ (row & 7))] = val;                           \
        }                                                                     \
    }                                                                         \
    if (t < 64) {                                                             \
        short4v h; h.x=f2bf(pft.x); h.y=f2bf(pft.y);                          \
        h.z=f2bf(pft.z); h.w=f2bf(pft.w);                                     \
        short* base = (short*)&EsS[t * 40 + (37 ^ (t & 7))];                  \
        *(short4v*)(base) = h;                                                \
        *(short4v*)(base + 4) = (short4v){0,0,0,0};                           \
    }                                                                         \
    if (t < 128) {                                                            \
        const int row = t >> 1, cc = 38 + (t & 1);                            \
        EsS[row * 40 + (cc ^ (row & 7))] = (short8){0,0,0,0,0,0,0,0};         \
    }                                                                         \
} while (0)

    // prologue: tile 0 staged, tile 1 prefetch in flight
    ISSUE_PF(slice);
    STAGE();
    ISSUE_PF(slice + NSLICE);
    __syncthreads();                               // B1

    for (int tt = 0; tt < ntiles; ++tt) {
        const int tile = slice + tt * NSLICE;
        const int v0   = tile * 64;

        // ---- k-loop: LDS A-frags (reg-dbuf) x register B-frags
        f32x4 acc0[5], acc1[5];
#pragma unroll
        for (int g = 0; g < 5; ++g) {
            acc0[g] = (f32x4){0.f, 0.f, 0.f, 0.f};
            acc1[g] = (f32x4){0.f, 0.f, 0.f, 0.f};
        }
        short8 afr[2][2];
        {
            const int kx = (kb + lk) ^ xmask;
            afr[0][0] = EsS[rb[0] + kx];
            afr[0][1] = EsS[rb[1] + kx];
        }
#pragma unroll
        for (int ks = 0; ks < 5; ++ks) {
            const int cur = ks & 1, nx = cur ^ 1;
            if (ks < 4) {
                const int kx = (kb + (ks + 1) * 4 + lk) ^ xmask;
                afr[nx][0] = EsS[rb[0] + kx];
                afr[nx][1] = EsS[rb[1] + kx];
            }
#pragma unroll
            for (int g = 0; g < 5; ++g) {
                acc0[g] = __builtin_amdgcn_mfma_f32_16x16x32_bf16(
                              afr[cur][0], bAll[g][ks], acc0[g], 0, 0, 0);
                acc1[g] = __builtin_amdgcn_mfma_f32_16x16x32_bf16(
                              afr[cur][1], bAll[g][ks], acc1[g], 0, 0, 0);
            }
        }
        __syncthreads();                           // B2: EsS reads done

        // ---- window: ship other-mt acc + stage next A + issue next prefetch
        if (kh == 0) {
#pragma unroll
            for (int g = 0; g < 5; ++g)
                Scr[((0 * 5 + g) * 4 + cell) * 64 + lid] = *(float4*)&acc1[g];
        } else {
#pragma unroll
            for (int g = 0; g < 5; ++g)
                Scr[((1 * 5 + g) * 4 + cell) * 64 + lid] = *(float4*)&acc0[g];
        }
        if (tt + 1 < ntiles) {
            STAGE();                               // stage tile tt+1
            ISSUE_PF(slice + (tt + 2) * NSLICE);   // prefetch tile tt+2
        }
        __syncthreads();                           // B3: scratch + staging done

        // ---- epilogue (split by kh): combine, tanh, dot b, shfl-reduce
        float part[4];
        if (kh == 0) {
#pragma unroll
            for (int i = 0; i < 4; ++i) {
                float p = 0.f;
#pragma unroll
                for (int g = 0; g < 5; ++g) {
                    float4 o = Scr[((1 * 5 + g) * 4 + cell) * 64 + lid];
                    float x  = acc0[g][i] + ((const float*)&o)[i];
                    float xc = fminf(fmaxf(x, -15.f), 15.f);
                    float e2 = __expf(2.f * xc);
                    p += __fdividef(e2 - 1.f, e2 + 1.f) * bcol[g];
                }
                part[i] = p;
            }
        } else {
#pragma unroll
            for (int i = 0; i < 4; ++i) {
                float p = 0.f;
#pragma unroll
                for (int g = 0; g < 5; ++g) {
                    float4 o = Scr[((0 * 5 + g) * 4 + cell) * 64 + lid];
                    float x  = acc1[g][i] + ((const float*)&o)[i];
                    float xc = fminf(fmaxf(x, -15.f), 15.f);
                    float e2 = __expf(2.f * xc);
                    p += __fdividef(e2 - 1.f, e2 + 1.f) * bcol[g];
                }
                part[i] = p;
            }
        }
#pragma unroll
        for (int m = 1; m <= 8; m <<= 1)
#pragma unroll
            for (int i = 0; i < 4; ++i)
                part[i] += __shfl_xor(part[i], m);
        if (lm == 0) {
#pragma unroll
            for (int i = 0; i < 4; ++i)
                Sred[ng * 64 + mg * 32 + kh * 16 + lk * 4 + i] = part[i];
        }
        __syncthreads();                           // B4: Sred ready

        if (t < 64) {
            const int v = v0 + t;
            if (v < VOCAB) {
                float* Sp = eh ? S1 : S0;
                Sp[v] = Sred[t] + Sred[64 + t];
            }
        }
    }
#undef ISSUE_PF
#undef STAGE
}

// ---------------------------------------------------------------------------
// attend: per token gather 20 neighbor scores (S0+S1), softmax, weighted sum.
// ---------------------------------------------------------------------------
__global__ __launch_bounds__(256) void attend_kernel(
    const int* __restrict__ text, const int* __restrict__ neighbors,
    const float* __restrict__ emb, const float* __restrict__ S0,
    const float* __restrict__ S1, float* __restrict__ out)
{
    const int lane = threadIdx.x & 63;
    const int wv   = threadIdx.x >> 6;
    const int tok  = blockIdx.x * 4 + wv;

    const int tid = text[tok];

    int   nbk = 0;
    float sc  = -1e30f;
    if (lane < TOPK) {
        nbk = neighbors[tid * TOPK + lane];
        sc  = S0[nbk] + S1[nbk];
    }

    float mx = sc;
#pragma unroll
    for (int m = 16; m >= 1; m >>= 1)
        mx = fmaxf(mx, __shfl_xor(mx, m));

    float ex = (lane < TOPK) ? expf(sc - mx) : 0.f;
    float sum = ex;
#pragma unroll
    for (int m = 16; m >= 1; m >>= 1)
        sum += __shfl_xor(sum, m);
    float att = ex / sum;

    float acc0 = 0.f, acc1 = 0.f, acc2 = 0.f, acc3 = 0.f, acc4 = 0.f;
    const bool has5 = (lane < EMB - 256);
#pragma unroll 4
    for (int k = 0; k < TOPK; ++k) {
        const float wgt = __shfl(att, k);
        const int   id  = __shfl(nbk, k);
        const float* row = emb + (size_t)id * EMB;
        acc0 = fmaf(wgt, row[lane      ], acc0);
        acc1 = fmaf(wgt, row[lane +  64], acc1);
        acc2 = fmaf(wgt, row[lane + 128], acc2);
        acc3 = fmaf(wgt, row[lane + 192], acc3);
        if (has5) acc4 = fmaf(wgt, row[lane + 256], acc4);
    }

    float* orow = out + (size_t)tok * EMB;
    orow[lane      ] = acc0;
    orow[lane +  64] = acc1;
    orow[lane + 128] = acc2;
    orow[lane + 192] = acc3;
    if (has5) orow[lane + 256] = acc4;
}

extern "C" void kernel_launch(void* const* d_in, const int* in_sizes, int n_in,
                              void* d_out, int out_size, void* d_ws, size_t ws_size,
                              hipStream_t stream) {
    const int*   text      = (const int*)d_in[0];
    const int*   neighbors = (const int*)d_in[1];
    const float* emb       = (const float*)d_in[2];
    const float* A         = (const float*)d_in[3];
    const float* B         = (const float*)d_in[4];
    float*       out       = (float*)d_out;

    char* ws = (char*)d_ws;
    float* S0 = (float*)ws;                 // 400,000 B
    float* S1 = (float*)(ws + 400000);      // 400,000 B
    short* aT = (short*)(ws + 800000);      // 204,800 B (16B-aligned)

    prep_kernel<<<320, 256, 0, stream>>>(A, aT);
    score_kernel<<<256, 512, 0, stream>>>(emb, aT, B, S0, S1);
    attend_kernel<<<NTOK / 4, 256, 0, stream>>>(text, neighbors, emb, S0, S1, out);
}

// Round 9
// 142.880 us; speedup vs baseline: 1.0016x; 1.0016x over previous
//
#include <hip/hip_runtime.h>
#include <hip/hip_bf16.h>
#include <math.h>

#define VOCAB 100000
#define TOPK  20
#define EMB   300
#define NTOK  (64*256)
#define NB    1563          // ceil(VOCAB/64) v-tiles
#define NSLICE 128          // v-tile slices (blocks per e-half)

typedef __attribute__((ext_vector_type(8))) short short8;   // 8 bf16 = 4 VGPR
typedef __attribute__((ext_vector_type(4))) short short4v;  // 8 B
typedef __attribute__((ext_vector_type(4))) float f32x4;

static __device__ inline short f2bf(float f) {
    __hip_bfloat16 h = __float2bfloat16(f);
    short s; __builtin_memcpy(&s, &h, 2);
    return s;
}

// ---------------------------------------------------------------------------
// prep: aT[e][d] = bf16(a[d][e]), zero-padded to 320x320.
// ---------------------------------------------------------------------------
__global__ void prep_kernel(const float* __restrict__ A, short* __restrict__ aT)
{
    const int e = blockIdx.x;                 // 0..319
    for (int d = threadIdx.x; d < 320; d += 256) {
        float f = (e < EMB && d < EMB) ? A[(size_t)d * EMB + e] : 0.f;
        aT[e * 320 + d] = f2bf(f);
    }
}

// ---------------------------------------------------------------------------
// score: s[v] = sum_e tanh( emb[v,:] . a[:,e] ) * b[e]  via bf16 MFMA.
// Persistent: 256 blocks (1/CU), block = (eh, slice). B-FRAGMENTS LIVE IN
// REGISTERS (bAll[5][5] short8 = 100 VGPR/lane, loaded once from L2-resident
// aT) -> k-loop reads ONLY A-frags from LDS (10 b128/wave/tile).
// r8 lesson: __launch_bounds__(512,2) capped VGPR at 128 (CUDA minBlocks
// semantics: 2 blocks -> 4 waves/SIMD -> 512/4=128) and spilled 12 MB to
// scratch. (512,1) -> 256-VGPR budget; peak concurrent ~220 -> no spill.
// Waves: 2mg x 2ng x 2kh; wave tile 32 rows x 80 cols, k-half 160.
// kh-exchange combine via 40 KB scratch; epilogue split across kh groups.
// ---------------------------------------------------------------------------
__global__ __launch_bounds__(512, 1) void score_kernel(
    const float* __restrict__ emb, const short* __restrict__ aT,
    const float* __restrict__ B, float* __restrict__ S0, float* __restrict__ S1)
{
    __shared__ short8 EsS[64 * 40];          // 40960 B : A tile (swizzled)
    __shared__ float4 Scr[2 * 5 * 4 * 64];   // 40960 B : kh-exchange scratch
    __shared__ float  Sred[128];

    const int t     = threadIdx.x;
    const int eh    = blockIdx.x >> 7;   // 0..1 e-half
    const int slice = blockIdx.x & 127;  // 0..127

    const int lid = t & 63;
    const int w   = t >> 6;        // 0..7
    const int kh  = w >> 2;        // k-half 0..1
    const int mg  = (w >> 1) & 1;  // m-pair
    const int ng  = w & 1;         // n-group
    const int lm  = lid & 15;
    const int lk  = lid >> 4;
    const int kb    = kh * 20;     // k-chunk base
    const int xmask = lm & 7;      // rowA%8 == lm%8
    const int cell  = mg * 2 + ng;

    // ---- B-fragments -> registers, once per block (25 x b128 from L2)
    const short8* aT8 = (const short8*)aT;
    short8 bAll[5][5];
#pragma unroll
    for (int g = 0; g < 5; ++g) {
        const int e = eh * 160 + ng * 80 + g * 16 + lm;
#pragma unroll
        for (int ks = 0; ks < 5; ++ks)
            bAll[g][ks] = aT8[e * 40 + kb + ks * 4 + lk];
    }

    float bcol[5];
#pragma unroll
    for (int g = 0; g < 5; ++g) {
        const int e = eh * 160 + ng * 80 + g * 16 + lm;
        bcol[g] = (e < EMB) ? B[e] : 0.f;
    }
    int rb[2];
#pragma unroll
    for (int mt = 0; mt < 2; ++mt)
        rb[mt] = (mg * 32 + mt * 16 + lm) * 40;

    const int ntiles = (NB - slice + NSLICE - 1) / NSLICE;

    // ---- A prefetch (registers): 2368 full pair-chunks + 64 tail float4
    float4 pf[5][2]; float4 pft;

#define ISSUE_PF(tn) do {                                                     \
    const float4* esrc = (const float4*)(emb + (size_t)(tn) * 64 * EMB);      \
    _Pragma("unroll")                                                         \
    for (int j = 0; j < 5; ++j) {                                             \
        const int i = t + j * 512;                                            \
        const int row = i / 37, cc = i - row * 37;                            \
        const bool ok = (i < 2368) && ((tn) * 64 + row < VOCAB);              \
        pf[j][0] = ok ? esrc[row * 75 + cc * 2]     : make_float4(0,0,0,0);   \
        pf[j][1] = ok ? esrc[row * 75 + cc * 2 + 1] : make_float4(0,0,0,0);   \
    }                                                                         \
    if (t < 64) pft = ((tn) * 64 + t < VOCAB) ? esrc[t * 75 + 74]             \
                                              : make_float4(0,0,0,0);         \
} while (0)

#define STAGE() do {                                                          \
    _Pragma("unroll")                                                         \
    for (int j = 0; j < 5; ++j) {                                             \
        const int i = t + j * 512;                                            \
        if (i < 2368) {                                                       \
            const int row = i / 37, cc = i - row * 37;                        \
            short8 val;                                                       \
            val[0]=f2bf(pf[j][0].x); val[1]=f2bf(pf[j][0].y);                 \
            val[2]=f2bf(pf[j][0].z); val[3]=f2bf(pf[j][0].w);                 \
            val[4]=f2bf(pf[j][1].x); val[5]=f2bf(pf[j][1].y);                 \
            val[6]=f2bf(pf[j][1].z); val[7]=f2bf(pf[j][1].w);                 \
            EsS[row * 40 + (cc ^ (row & 7))] = val;                           \
        }                                                                     \
    }                                                                         \
    if (t < 64) {                                                             \
        short4v h; h.x=f2bf(pft.x); h.y=f2bf(pft.y);                          \
        h.z=f2bf(pft.z); h.w=f2bf(pft.w);                                     \
        short* base = (short*)&EsS[t * 40 + (37 ^ (t & 7))];                  \
        *(short4v*)(base) = h;                                                \
        *(short4v*)(base + 4) = (short4v){0,0,0,0};                           \
    }                                                                         \
    if (t < 128) {                                                            \
        const int row = t >> 1, cc = 38 + (t & 1);                            \
        EsS[row * 40 + (cc ^ (row & 7))] = (short8){0,0,0,0,0,0,0,0};         \
    }                                                                         \
} while (0)

    // prologue: tile 0 staged, tile 1 prefetch in flight
    ISSUE_PF(slice);
    STAGE();
    ISSUE_PF(slice + NSLICE);
    __syncthreads();                               // B1

    for (int tt = 0; tt < ntiles; ++tt) {
        const int tile = slice + tt * NSLICE;
        const int v0   = tile * 64;

        // ---- k-loop: LDS A-frags (reg-dbuf) x register B-frags
        f32x4 acc0[5], acc1[5];
#pragma unroll
        for (int g = 0; g < 5; ++g) {
            acc0[g] = (f32x4){0.f, 0.f, 0.f, 0.f};
            acc1[g] = (f32x4){0.f, 0.f, 0.f, 0.f};
        }
        short8 afr[2][2];
        {
            const int kx = (kb + lk) ^ xmask;
            afr[0][0] = EsS[rb[0] + kx];
            afr[0][1] = EsS[rb[1] + kx];
        }
#pragma unroll
        for (int ks = 0; ks < 5; ++ks) {
            const int cur = ks & 1, nx = cur ^ 1;
            if (ks < 4) {
                const int kx = (kb + (ks + 1) * 4 + lk) ^ xmask;
                afr[nx][0] = EsS[rb[0] + kx];
                afr[nx][1] = EsS[rb[1] + kx];
            }
#pragma unroll
            for (int g = 0; g < 5; ++g) {
                acc0[g] = __builtin_amdgcn_mfma_f32_16x16x32_bf16(
                              afr[cur][0], bAll[g][ks], acc0[g], 0, 0, 0);
                acc1[g] = __builtin_amdgcn_mfma_f32_16x16x32_bf16(
                              afr[cur][1], bAll[g][ks], acc1[g], 0, 0, 0);
            }
        }
        __syncthreads();                           // B2: EsS reads done

        // ---- window: ship other-mt acc + stage next A + issue next prefetch
        if (kh == 0) {
#pragma unroll
            for (int g = 0; g < 5; ++g)
                Scr[((0 * 5 + g) * 4 + cell) * 64 + lid] = *(float4*)&acc1[g];
        } else {
#pragma unroll
            for (int g = 0; g < 5; ++g)
                Scr[((1 * 5 + g) * 4 + cell) * 64 + lid] = *(float4*)&acc0[g];
        }
        if (tt + 1 < ntiles) {
            STAGE();                               // stage tile tt+1
            ISSUE_PF(slice + (tt + 2) * NSLICE);   // prefetch tile tt+2
        }
        __syncthreads();                           // B3: scratch + staging done

        // ---- epilogue (split by kh): combine, tanh, dot b, shfl-reduce
        float part[4];
        if (kh == 0) {
#pragma unroll
            for (int i = 0; i < 4; ++i) {
                float p = 0.f;
#pragma unroll
                for (int g = 0; g < 5; ++g) {
                    float4 o = Scr[((1 * 5 + g) * 4 + cell) * 64 + lid];
                    float x  = acc0[g][i] + ((const float*)&o)[i];
                    float xc = fminf(fmaxf(x, -15.f), 15.f);
                    float e2 = __expf(2.f * xc);
                    p += __fdividef(e2 - 1.f, e2 + 1.f) * bcol[g];
                }
                part[i] = p;
            }
        } else {
#pragma unroll
            for (int i = 0; i < 4; ++i) {
                float p = 0.f;
#pragma unroll
                for (int g = 0; g < 5; ++g) {
                    float4 o = Scr[((0 * 5 + g) * 4 + cell) * 64 + lid];
                    float x  = acc1[g][i] + ((const float*)&o)[i];
                    float xc = fminf(fmaxf(x, -15.f), 15.f);
                    float e2 = __expf(2.f * xc);
                    p += __fdividef(e2 - 1.f, e2 + 1.f) * bcol[g];
                }
                part[i] = p;
            }
        }
#pragma unroll
        for (int m = 1; m <= 8; m <<= 1)
#pragma unroll
            for (int i = 0; i < 4; ++i)
                part[i] += __shfl_xor(part[i], m);
        if (lm == 0) {
#pragma unroll
            for (int i = 0; i < 4; ++i)
                Sred[ng * 64 + mg * 32 + kh * 16 + lk * 4 + i] = part[i];
        }
        __syncthreads();                           // B4: Sred ready

        if (t < 64) {
            const int v = v0 + t;
            if (v < VOCAB) {
                float* Sp = eh ? S1 : S0;
                Sp[v] = Sred[t] + Sred[64 + t];
            }
        }
    }
#undef ISSUE_PF
#undef STAGE
}

// ---------------------------------------------------------------------------
// attend: per token gather 20 neighbor scores (S0+S1), softmax, weighted sum.
// ---------------------------------------------------------------------------
__global__ __launch_bounds__(256) void attend_kernel(
    const int* __restrict__ text, const int* __restrict__ neighbors,
    const float* __restrict__ emb, const float* __restrict__ S0,
    const float* __restrict__ S1, float* __restrict__ out)
{
    const int lane = threadIdx.x & 63;
    const int wv   = threadIdx.x >> 6;
    const int tok  = blockIdx.x * 4 + wv;

    const int tid = text[tok];

    int   nbk = 0;
    float sc  = -1e30f;
    if (lane < TOPK) {
        nbk = neighbors[tid * TOPK + lane];
        sc  = S0[nbk] + S1[nbk];
    }

    float mx = sc;
#pragma unroll
    for (int m = 16; m >= 1; m >>= 1)
        mx = fmaxf(mx, __shfl_xor(mx, m));

    float ex = (lane < TOPK) ? expf(sc - mx) : 0.f;
    float sum = ex;
#pragma unroll
    for (int m = 16; m >= 1; m >>= 1)
        sum += __shfl_xor(sum, m);
    float att = ex / sum;

    float acc0 = 0.f, acc1 = 0.f, acc2 = 0.f, acc3 = 0.f, acc4 = 0.f;
    const bool has5 = (lane < EMB - 256);
#pragma unroll 4
    for (int k = 0; k < TOPK; ++k) {
        const float wgt = __shfl(att, k);
        const int   id  = __shfl(nbk, k);
        const float* row = emb + (size_t)id * EMB;
        acc0 = fmaf(wgt, row[lane      ], acc0);
        acc1 = fmaf(wgt, row[lane +  64], acc1);
        acc2 = fmaf(wgt, row[lane + 128], acc2);
        acc3 = fmaf(wgt, row[lane + 192], acc3);
        if (has5) acc4 = fmaf(wgt, row[lane + 256], acc4);
    }

    float* orow = out + (size_t)tok * EMB;
    orow[lane      ] = acc0;
    orow[lane +  64] = acc1;
    orow[lane + 128] = acc2;
    orow[lane + 192] = acc3;
    if (has5) orow[lane + 256] = acc4;
}

extern "C" void kernel_launch(void* const* d_in, const int* in_sizes, int n_in,
                              void* d_out, int out_size, void* d_ws, size_t ws_size,
                              hipStream_t stream) {
    const int*   text      = (const int*)d_in[0];
    const int*   neighbors = (const int*)d_in[1];
    const float* emb       = (const float*)d_in[2];
    const float* A         = (const float*)d_in[3];
    const float* B         = (const float*)d_in[4];
    float*       out       = (float*)d_out;

    char* ws = (char*)d_ws;
    float* S0 = (float*)ws;                 // 400,000 B
    float* S1 = (float*)(ws + 400000);      // 400,000 B
    short* aT = (short*)(ws + 800000);      // 204,800 B (16B-aligned)

    prep_kernel<<<320, 256, 0, stream>>>(A, aT);
    score_kernel<<<256, 512, 0, stream>>>(emb, aT, B, S0, S1);
    attend_kernel<<<NTOK / 4, 256, 0, stream>>>(text, neighbors, emb, S0, S1, out);
}

// Round 10
// 142.795 us; speedup vs baseline: 1.0022x; 1.0006x over previous
//
#include <hip/hip_runtime.h>
#include <hip/hip_bf16.h>
#include <math.h>

#define VOCAB 100000
#define TOPK  20
#define EMB   300
#define NTOK  (64*256)
#define NB    1563          // ceil(VOCAB/64) v-tiles
#define NSLICE 128          // v-tile slices (blocks per e-half)

typedef __attribute__((ext_vector_type(8))) short short8;   // 8 bf16 = 4 VGPR
typedef __attribute__((ext_vector_type(4))) short short4v;  // 8 B
typedef __attribute__((ext_vector_type(4))) float f32x4;

static __device__ inline short f2bf(float f) {
    __hip_bfloat16 h = __float2bfloat16(f);
    short s; __builtin_memcpy(&s, &h, 2);
    return s;
}

// ---------------------------------------------------------------------------
// prep: aT[e][d] = bf16(a[d][e]), zero-padded to 320x320.
// ---------------------------------------------------------------------------
__global__ void prep_kernel(const float* __restrict__ A, short* __restrict__ aT)
{
    const int e = blockIdx.x;                 // 0..319
    for (int d = threadIdx.x; d < 320; d += 256) {
        float f = (e < EMB && d < EMB) ? A[(size_t)d * EMB + e] : 0.f;
        aT[e * 320 + d] = f2bf(f);
    }
}

// ---------------------------------------------------------------------------
// score: s[v] = sum_e tanh( emb[v,:] . a[:,e] ) * b[e]  via bf16 MFMA.
// Persistent: 256 blocks (1/CU), block = (eh, slice). B-FRAGMENTS LIVE IN
// REGISTERS (bAll[5][5] short8 = 100 VGPR/lane, loaded once from L2-resident
// aT) -> k-loop reads ONLY A-frags from LDS (10 b128/wave/tile).
// r8/r9 lesson: __launch_bounds__(512,{1,2}) both left the allocator at its
// default 4-waves/EU target -> 128-VGPR cap -> ~90 regs spilled (12 MB
// scratch writes/dispatch). Fix: pin occupancy with amdgpu_waves_per_eu(2,2)
// -> budget = 512-reg pool / 2 = 256 VGPR. 8-wave workgroup forces 2
// waves/SIMD residency anyway, so no occupancy is lost.
// Waves: 2mg x 2ng x 2kh; wave tile 32 rows x 80 cols, k-half 160.
// kh-exchange combine via 40 KB scratch; epilogue split across kh groups.
// ---------------------------------------------------------------------------
__global__ __attribute__((amdgpu_flat_work_group_size(512, 512),
                          amdgpu_waves_per_eu(2, 2)))
void score_kernel(
    const float* __restrict__ emb, const short* __restrict__ aT,
    const float* __restrict__ B, float* __restrict__ S0, float* __restrict__ S1)
{
    __shared__ short8 EsS[64 * 40];          // 40960 B : A tile (swizzled)
    __shared__ float4 Scr[2 * 5 * 4 * 64];   // 40960 B : kh-exchange scratch
    __shared__ float  Sred[128];

    const int t     = threadIdx.x;
    const int eh    = blockIdx.x >> 7;   // 0..1 e-half
    const int slice = blockIdx.x & 127;  // 0..127

    const int lid = t & 63;
    const int w   = t >> 6;        // 0..7
    const int kh  = w >> 2;        // k-half 0..1
    const int mg  = (w >> 1) & 1;  // m-pair
    const int ng  = w & 1;         // n-group
    const int lm  = lid & 15;
    const int lk  = lid >> 4;
    const int kb    = kh * 20;     // k-chunk base
    const int xmask = lm & 7;      // rowA%8 == lm%8
    const int cell  = mg * 2 + ng;

    // ---- B-fragments -> registers, once per block (25 x b128 from L2)
    const short8* aT8 = (const short8*)aT;
    short8 bAll[5][5];
#pragma unroll
    for (int g = 0; g < 5; ++g) {
        const int e = eh * 160 + ng * 80 + g * 16 + lm;
#pragma unroll
        for (int ks = 0; ks < 5; ++ks)
            bAll[g][ks] = aT8[e * 40 + kb + ks * 4 + lk];
    }

    float bcol[5];
#pragma unroll
    for (int g = 0; g < 5; ++g) {
        const int e = eh * 160 + ng * 80 + g * 16 + lm;
        bcol[g] = (e < EMB) ? B[e] : 0.f;
    }
    int rb[2];
#pragma unroll
    for (int mt = 0; mt < 2; ++mt)
        rb[mt] = (mg * 32 + mt * 16 + lm) * 40;

    const int ntiles = (NB - slice + NSLICE - 1) / NSLICE;

    // ---- A prefetch (registers): 2368 full pair-chunks + 64 tail float4
    float4 pf[5][2]; float4 pft;

#define ISSUE_PF(tn) do {                                                     \
    const float4* esrc = (const float4*)(emb + (size_t)(tn) * 64 * EMB);      \
    _Pragma("unroll")                                                         \
    for (int j = 0; j < 5; ++j) {                                             \
        const int i = t + j * 512;                                            \
        const int row = i / 37, cc = i - row * 37;                            \
        const bool ok = (i < 2368) && ((tn) * 64 + row < VOCAB);              \
        pf[j][0] = ok ? esrc[row * 75 + cc * 2]     : make_float4(0,0,0,0);   \
        pf[j][1] = ok ? esrc[row * 75 + cc * 2 + 1] : make_float4(0,0,0,0);   \
    }                                                                         \
    if (t < 64) pft = ((tn) * 64 + t < VOCAB) ? esrc[t * 75 + 74]             \
                                              : make_float4(0,0,0,0);         \
} while (0)

#define STAGE() do {                                                          \
    _Pragma("unroll")                                                         \
    for (int j = 0; j < 5; ++j) {                                             \
        const int i = t + j * 512;                                            \
        if (i < 2368) {                                                       \
            const int row = i / 37, cc = i - row * 37;                        \
            short8 val;                                                       \
            val[0]=f2bf(pf[j][0].x); val[1]=f2bf(pf[j][0].y);                 \
            val[2]=f2bf(pf[j][0].z); val[3]=f2bf(pf[j][0].w);                 \
            val[4]=f2bf(pf[j][1].x); val[5]=f2bf(pf[j][1].y);                 \
            val[6]=f2bf(pf[j][1].z); val[7]=f2bf(pf[j][1].w);                 \
            EsS[row * 40 + (cc ^ (row & 7))] = val;                           \
        }                                                                     \
    }                                                                         \
    if (t < 64) {                                                             \
        short4v h; h.x=f2bf(pft.x); h.y=f2bf(pft.y);                          \
        h.z=f2bf(pft.z); h.w=f2bf(pft.w);                                     \
        short* base = (short*)&EsS[t * 40 + (37 ^ (t & 7))];                  \
        *(short4v*)(base) = h;                                                \
        *(short4v*)(base + 4) = (short4v){0,0,0,0};                           \
    }                                                                         \
    if (t < 128) {                                                            \
        const int row = t >> 1, cc = 38 + (t & 1);                            \
        EsS[row * 40 + (cc ^ (row & 7))] = (short8){0,0,0,0,0,0,0,0};         \
    }                                                                         \
} while (0)

    // prologue: tile 0 staged, tile 1 prefetch in flight
    ISSUE_PF(slice);
    STAGE();
    ISSUE_PF(slice + NSLICE);
    __syncthreads();                               // B1

    for (int tt = 0; tt < ntiles; ++tt) {
        const int tile = slice + tt * NSLICE;
        const int v0   = tile * 64;

        // ---- k-loop: LDS A-frags (reg-dbuf) x register B-frags
        f32x4 acc0[5], acc1[5];
#pragma unroll
        for (int g = 0; g < 5; ++g) {
            acc0[g] = (f32x4){0.f, 0.f, 0.f, 0.f};
            acc1[g] = (f32x4){0.f, 0.f, 0.f, 0.f};
        }
        short8 afr[2][2];
        {
            const int kx = (kb + lk) ^ xmask;
            afr[0][0] = EsS[rb[0] + kx];
            afr[0][1] = EsS[rb[1] + kx];
        }
#pragma unroll
        for (int ks = 0; ks < 5; ++ks) {
            const int cur = ks & 1, nx = cur ^ 1;
            if (ks < 4) {
                const int kx = (kb + (ks + 1) * 4 + lk) ^ xmask;
                afr[nx][0] = EsS[rb[0] + kx];
                afr[nx][1] = EsS[rb[1] + kx];
            }
#pragma unroll
            for (int g = 0; g < 5; ++g) {
                acc0[g] = __builtin_amdgcn_mfma_f32_16x16x32_bf16(
                              afr[cur][0], bAll[g][ks], acc0[g], 0, 0, 0);
                acc1[g] = __builtin_amdgcn_mfma_f32_16x16x32_bf16(
                              afr[cur][1], bAll[g][ks], acc1[g], 0, 0, 0);
            }
        }
        __syncthreads();                           // B2: EsS reads done

        // ---- window: ship other-mt acc + stage next A + issue next prefetch
        if (kh == 0) {
#pragma unroll
            for (int g = 0; g < 5; ++g)
                Scr[((0 * 5 + g) * 4 + cell) * 64 + lid] = *(float4*)&acc1[g];
        } else {
#pragma unroll
            for (int g = 0; g < 5; ++g)
                Scr[((1 * 5 + g) * 4 + cell) * 64 + lid] = *(float4*)&acc0[g];
        }
        if (tt + 1 < ntiles) {
            STAGE();                               // stage tile tt+1
            ISSUE_PF(slice + (tt + 2) * NSLICE);   // prefetch tile tt+2
        }
        __syncthreads();                           // B3: scratch + staging done

        // ---- epilogue (split by kh): combine, tanh, dot b, shfl-reduce
        float part[4];
        if (kh == 0) {
#pragma unroll
            for (int i = 0; i < 4; ++i) {
                float p = 0.f;
#pragma unroll
                for (int g = 0; g < 5; ++g) {
                    float4 o = Scr[((1 * 5 + g) * 4 + cell) * 64 + lid];
                    float x  = acc0[g][i] + ((const float*)&o)[i];
                    float xc = fminf(fmaxf(x, -15.f), 15.f);
                    float e2 = __expf(2.f * xc);
                    p += __fdividef(e2 - 1.f, e2 + 1.f) * bcol[g];
                }
                part[i] = p;
            }
        } else {
#pragma unroll
            for (int i = 0; i < 4; ++i) {
                float p = 0.f;
#pragma unroll
                for (int g = 0; g < 5; ++g) {
                    float4 o = Scr[((0 * 5 + g) * 4 + cell) * 64 + lid];
                    float x  = acc1[g][i] + ((const float*)&o)[i];
                    float xc = fminf(fmaxf(x, -15.f), 15.f);
                    float e2 = __expf(2.f * xc);
                    p += __fdividef(e2 - 1.f, e2 + 1.f) * bcol[g];
                }
                part[i] = p;
            }
        }
#pragma unroll
        for (int m = 1; m <= 8; m <<= 1)
#pragma unroll
            for (int i = 0; i < 4; ++i)
                part[i] += __shfl_xor(part[i], m);
        if (lm == 0) {
#pragma unroll
            for (int i = 0; i < 4; ++i)
                Sred[ng * 64 + mg * 32 + kh * 16 + lk * 4 + i] = part[i];
        }
        __syncthreads();                           // B4: Sred ready

        if (t < 64) {
            const int v = v0 + t;
            if (v < VOCAB) {
                float* Sp = eh ? S1 : S0;
                Sp[v] = Sred[t] + Sred[64 + t];
            }
        }
    }
#undef ISSUE_PF
#undef STAGE
}

// ---------------------------------------------------------------------------
// attend: per token gather 20 neighbor scores (S0+S1), softmax, weighted sum.
// ---------------------------------------------------------------------------
__global__ __launch_bounds__(256) void attend_kernel(
    const int* __restrict__ text, const int* __restrict__ neighbors,
    const float* __restrict__ emb, const float* __restrict__ S0,
    const float* __restrict__ S1, float* __restrict__ out)
{
    const int lane = threadIdx.x & 63;
    const int wv   = threadIdx.x >> 6;
    const int tok  = blockIdx.x * 4 + wv;

    const int tid = text[tok];

    int   nbk = 0;
    float sc  = -1e30f;
    if (lane < TOPK) {
        nbk = neighbors[tid * TOPK + lane];
        sc  = S0[nbk] + S1[nbk];
    }

    float mx = sc;
#pragma unroll
    for (int m = 16; m >= 1; m >>= 1)
        mx = fmaxf(mx, __shfl_xor(mx, m));

    float ex = (lane < TOPK) ? expf(sc - mx) : 0.f;
    float sum = ex;
#pragma unroll
    for (int m = 16; m >= 1; m >>= 1)
        sum += __shfl_xor(sum, m);
    float att = ex / sum;

    float acc0 = 0.f, acc1 = 0.f, acc2 = 0.f, acc3 = 0.f, acc4 = 0.f;
    const bool has5 = (lane < EMB - 256);
#pragma unroll 4
    for (int k = 0; k < TOPK; ++k) {
        const float wgt = __shfl(att, k);
        const int   id  = __shfl(nbk, k);
        const float* row = emb + (size_t)id * EMB;
        acc0 = fmaf(wgt, row[lane      ], acc0);
        acc1 = fmaf(wgt, row[lane +  64], acc1);
        acc2 = fmaf(wgt, row[lane + 128], acc2);
        acc3 = fmaf(wgt, row[lane + 192], acc3);
        if (has5) acc4 = fmaf(wgt, row[lane + 256], acc4);
    }

    float* orow = out + (size_t)tok * EMB;
    orow[lane      ] = acc0;
    orow[lane +  64] = acc1;
    orow[lane + 128] = acc2;
    orow[lane + 192] = acc3;
    if (has5) orow[lane + 256] = acc4;
}

extern "C" void kernel_launch(void* const* d_in, const int* in_sizes, int n_in,
                              void* d_out, int out_size, void* d_ws, size_t ws_size,
                              hipStream_t stream) {
    const int*   text      = (const int*)d_in[0];
    const int*   neighbors = (const int*)d_in[1];
    const float* emb       = (const float*)d_in[2];
    const float* A         = (const float*)d_in[3];
    const float* B         = (const float*)d_in[4];
    float*       out       = (float*)d_out;

    char* ws = (char*)d_ws;
    float* S0 = (float*)ws;                 // 400,000 B
    float* S1 = (float*)(ws + 400000);      // 400,000 B
    short* aT = (short*)(ws + 800000);      // 204,800 B (16B-aligned)

    prep_kernel<<<320, 256, 0, stream>>>(A, aT);
    score_kernel<<<256, 512, 0, stream>>>(emb, aT, B, S0, S1);
    attend_kernel<<<NTOK / 4, 256, 0, stream>>>(text, neighbors, emb, S0, S1, out);
}